// Round 23
// baseline (223.528 us; speedup 1.0000x reference)
//
#include <hip/hip_runtime.h>
#include <math.h>

#define N_NODES 50000
#define N_EDGES 800000
#define ETOT    (N_EDGES + N_NODES)
#define DH      128
#define NH      4
#define LN_EPS  1e-5f
#define NBLK    ((N_NODES + 255) / 256)   // 196 blocks
#define LOG2E   1.4426950408889634f

typedef __attribute__((ext_vector_type(8))) short short8;
typedef __attribute__((ext_vector_type(8))) unsigned short ushort8v;
typedef __attribute__((ext_vector_type(4))) float f32x4;
typedef __attribute__((ext_vector_type(4))) unsigned uint4v;

// ---------- fp32 -> bf16 (RNE) helpers ----------
__device__ __forceinline__ unsigned short f2bf(float f) {
    unsigned u = __float_as_uint(f);
    u += 0x7FFFu + ((u >> 16) & 1u);
    return (unsigned short)(u >> 16);
}
__device__ __forceinline__ float bf2f(unsigned short h) {
    return __uint_as_float(((unsigned)h) << 16);
}
__device__ __forceinline__ unsigned pk_bf16(float a, float b) {
    unsigned h;
    asm("v_cvt_pk_bf16_f32 %0, %1, %2" : "=v"(h) : "v"(a), "v"(b));
    return h;
}

// ---------- fast exact-GELU (A&S 7.1.26 erf, max err ~1.5e-7) ----------
__device__ __forceinline__ float gelu_exact(float x) {
    const float z  = x * 0.70710678118654752f;
    const float az = fabsf(z);
    const float tt = __builtin_amdgcn_rcpf(fmaf(0.3275911f, az, 1.f));
    float p = fmaf(1.061405429f, tt, -1.453152027f);
    p = fmaf(p, tt, 1.421413741f);
    p = fmaf(p, tt, -0.284496736f);
    p = fmaf(p, tt, 0.254829592f);
    p = p * tt;
    const float ez = exp2f(-(z * z) * LOG2E);
    float er = fmaf(-p, ez, 1.f);
    er = copysignf(er, z);
    return x * fmaf(0.5f, er, 0.5f);
}

// ===== fused prep+degree, INTERLEAVED block ranges =====
#define DRBLK  ((ETOT + 255) / 256)        // 3321
#define PPARTS (320 + 3125)                // 3445
__global__ __launch_bounds__(256) void prep_degree_kernel(
    const float* __restrict__ W0, const float* __restrict__ W1,
    const float* __restrict__ W2, const float* __restrict__ W3,
    const float* __restrict__ W4,
    short* __restrict__ hi,
    const float* __restrict__ X, unsigned short* __restrict__ Xb,
    const int* __restrict__ eidx, int* __restrict__ deg,
    unsigned short* __restrict__ rank16)
{
    const int b = blockIdx.x;
    int pp = -1;
    if (b < 2 * DRBLK) {
        if (b & 1) {
            const int i = (b >> 1) * 256 + threadIdx.x;
            if (i < ETOT) {
                const int d = (i < N_EDGES) ? eidx[N_EDGES + i] : (i - N_EDGES);
                rank16[i] = (unsigned short)atomicAdd(&deg[d], 1);
            }
            return;
        }
        pp = b >> 1;
    } else {
        pp = b - DRBLK;   // 3321..3444
    }
    if (pp < 320) {
        const int idx = pp * 256 + threadIdx.x;   // 0..81919
        const int mat = idx >> 14;
        const int rem = idx & 16383;
        const int t = rem >> 12, c = (rem >> 9) & 7, l = (rem >> 3) & 63, j = rem & 7;
        const int k = t * 32 + (l >> 4) * 8 + j;
        const int n = c * 16 + (l & 15);
        const float* W = (mat == 0) ? W0 : (mat == 1) ? W1 : (mat == 2) ? W2
                       : (mat == 3) ? W3 : W4;
        hi[idx] = (short)f2bf(W[k * DH + n]);
    } else {
        const size_t i = ((size_t)(pp - 320) * 256 + threadIdx.x) * 8;   // NF = 3125*2048
        const float4 f0 = *(const float4*)(X + i);
        const float4 f1 = *(const float4*)(X + i + 4);
        uint4v o;
        o[0] = pk_bf16(f0.x, f0.y);
        o[1] = pk_bf16(f0.z, f0.w);
        o[2] = pk_bf16(f1.x, f1.y);
        o[3] = pk_bf16(f1.z, f1.w);
        *(uint4v*)(Xb + i) = o;
    }
}

// ===== single-kernel rowptr: block b computes base = sum(deg[0..b*256)) directly =====
__global__ __launch_bounds__(256) void rowptr_kernel(
    const int* __restrict__ deg, int* __restrict__ rowptr)
{
    const int b    = blockIdx.x;
    const int tid  = threadIdx.x;
    const int lane = tid & 63;
    const int wid  = tid >> 6;

    // strided reduce over deg[0 .. b*256)
    int bv = 0;
    const int lim = b * 256;
    for (int i = tid; i < lim; i += 256) bv += deg[i];
    #pragma unroll
    for (int off = 32; off; off >>= 1) bv += __shfl_xor(bv, off);
    __shared__ int ws2[4];
    __shared__ int boffs;
    if (lane == 0) ws2[wid] = bv;
    __syncthreads();
    if (tid == 0) boffs = ws2[0] + ws2[1] + ws2[2] + ws2[3];
    __syncthreads();
    const int boff = boffs;

    const int i = b * 256 + tid;
    int v = (i < N_NODES) ? deg[i] : 0;
    int inc = v;
    #pragma unroll
    for (int off = 1; off < 64; off <<= 1) {
        int u = __shfl_up(inc, off);
        if (lane >= off) inc += u;
    }
    __shared__ int ws[4];
    if (lane == 63) ws[wid] = inc;
    __syncthreads();
    int add = boff;
    for (int w = 0; w < wid; ++w) add += ws[w];
    if (i < N_NODES) rowptr[i] = add + inc - v;
}

// ========== fused: atomic-free scatter + layer-0 dual GEMM (bf16 W) ==========
#define GTILE 64
#define SCBLK ((ETOT / 8 + 255) / 256)   // 416
__global__ __launch_bounds__(256) void scatter_gemm2_kernel(
    const int* __restrict__ eidx, const int* __restrict__ rowptr,
    const unsigned short* __restrict__ rank16, unsigned short* __restrict__ csr_src,
    const unsigned short* __restrict__ A, int m_rows,
    const short* __restrict__ WhL, const float* __restrict__ biasL,
    unsigned short* __restrict__ YL,
    const short* __restrict__ WhR, const float* __restrict__ biasR,
    unsigned short* __restrict__ YR)
{
    if (blockIdx.x < SCBLK) {
        const int base = (blockIdx.x * 256 + threadIdx.x) * 8;
        if (base < N_EDGES) {
            const int4 s0 = *(const int4*)(eidx + base);
            const int4 s1 = *(const int4*)(eidx + base + 4);
            const int4 d0 = *(const int4*)(eidx + N_EDGES + base);
            const int4 d1 = *(const int4*)(eidx + N_EDGES + base + 4);
            const ushort8v rk = *(const ushort8v*)(rank16 + base);
            csr_src[rowptr[d0.x] + rk[0]] = (unsigned short)s0.x;
            csr_src[rowptr[d0.y] + rk[1]] = (unsigned short)s0.y;
            csr_src[rowptr[d0.z] + rk[2]] = (unsigned short)s0.z;
            csr_src[rowptr[d0.w] + rk[3]] = (unsigned short)s0.w;
            csr_src[rowptr[d1.x] + rk[4]] = (unsigned short)s1.x;
            csr_src[rowptr[d1.y] + rk[5]] = (unsigned short)s1.y;
            csr_src[rowptr[d1.z] + rk[6]] = (unsigned short)s1.z;
            csr_src[rowptr[d1.w] + rk[7]] = (unsigned short)s1.w;
        } else if (base < ETOT) {
            const int d0 = base - N_EDGES;
            const ushort8v rk = *(const ushort8v*)(rank16 + base);
            #pragma unroll
            for (int k = 0; k < 8; ++k)
                csr_src[rowptr[d0 + k] + rk[k]] = (unsigned short)(d0 + k);
        }
        return;
    }

    const int gb   = blockIdx.x - SCBLK;
    const int w    = threadIdx.x >> 6;
    const int lane = threadIdx.x & 63;
    const int rows0 = (gb >> 1) * GTILE + w * 16;
    const int ch   = gb & 1;
    const int g  = lane >> 4;
    const int rl = lane & 15;

    f32x4 accL[4], accR[4];
    #pragma unroll
    for (int c = 0; c < 4; ++c) {
        accL[c] = (f32x4){0.f, 0.f, 0.f, 0.f};
        accR[c] = (f32x4){0.f, 0.f, 0.f, 0.f};
    }

    for (int t = 0; t < 4; ++t) {
        int arow = rows0 + rl;
        arow = (arow < m_rows) ? arow : (m_rows - 1);
        const short8 a = *(const short8*)(A + (size_t)arow * DH + t * 32 + g * 8);
        #pragma unroll
        for (int c = 0; c < 4; ++c) {
            const int cc = ch * 4 + c;
            const int fidx = ((t * 8 + cc) * 64 + lane) * 8;
            const short8 bL = *(const short8*)(WhL + fidx);
            const short8 bR = *(const short8*)(WhR + fidx);
            accL[c] = __builtin_amdgcn_mfma_f32_16x16x32_bf16(a, bL, accL[c], 0, 0, 0);
            accR[c] = __builtin_amdgcn_mfma_f32_16x16x32_bf16(a, bR, accR[c], 0, 0, 0);
        }
    }
    #pragma unroll
    for (int c = 0; c < 4; ++c) {
        const int col = (ch * 4 + c) * 16 + rl;
        const float bL = biasL[col];
        const float bR = biasR[col];
        #pragma unroll
        for (int q = 0; q < 4; ++q) {
            const int row = rows0 + g * 4 + q;
            if (row < m_rows) {
                YL[(size_t)row * DH + col] = f2bf(accL[c][q] + bL);
                YR[(size_t)row * DH + col] = f2bf(accR[c][q] + bR);
            }
        }
    }
}

// ========== standalone dual GEMM (layer 1, bf16 W) ==========
__global__ __launch_bounds__(256) void gemm2_kernel(
    const unsigned short* __restrict__ A, int m_rows,
    const short* __restrict__ WhL, const float* __restrict__ biasL,
    unsigned short* __restrict__ YL,
    const short* __restrict__ WhR, const float* __restrict__ biasR,
    unsigned short* __restrict__ YR)
{
    const int w    = threadIdx.x >> 6;
    const int lane = threadIdx.x & 63;
    const int rows0 = blockIdx.x * GTILE + w * 16;
    const int ch   = blockIdx.y;
    const int g  = lane >> 4;
    const int rl = lane & 15;

    f32x4 accL[4], accR[4];
    #pragma unroll
    for (int c = 0; c < 4; ++c) {
        accL[c] = (f32x4){0.f, 0.f, 0.f, 0.f};
        accR[c] = (f32x4){0.f, 0.f, 0.f, 0.f};
    }

    for (int t = 0; t < 4; ++t) {
        int arow = rows0 + rl;
        arow = (arow < m_rows) ? arow : (m_rows - 1);
        const short8 a = *(const short8*)(A + (size_t)arow * DH + t * 32 + g * 8);
        #pragma unroll
        for (int c = 0; c < 4; ++c) {
            const int cc = ch * 4 + c;
            const int fidx = ((t * 8 + cc) * 64 + lane) * 8;
            const short8 bL = *(const short8*)(WhL + fidx);
            const short8 bR = *(const short8*)(WhR + fidx);
            accL[c] = __builtin_amdgcn_mfma_f32_16x16x32_bf16(a, bL, accL[c], 0, 0, 0);
            accR[c] = __builtin_amdgcn_mfma_f32_16x16x32_bf16(a, bR, accR[c], 0, 0, 0);
        }
    }
    #pragma unroll
    for (int c = 0; c < 4; ++c) {
        const int col = (ch * 4 + c) * 16 + rl;
        const float bL = biasL[col];
        const float bR = biasR[col];
        #pragma unroll
        for (int q = 0; q < 4; ++q) {
            const int row = rows0 + g * 4 + q;
            if (row < m_rows) {
                YL[(size_t)row * DH + col] = f2bf(accL[c][q] + bL);
                YR[(size_t)row * DH + col] = f2bf(accR[c][q] + bR);
            }
        }
    }
}

// ========== gemm1 + fused final LayerNorm: 16 rows/wave (bf16 W) ==========
__global__ __launch_bounds__(256) void gemm1_ln_kernel(
    const unsigned short* __restrict__ A, int m_rows,
    const short* __restrict__ Wh, const float* __restrict__ bias,
    const float* __restrict__ gam, const float* __restrict__ bet,
    float* __restrict__ out)
{
    const int w    = threadIdx.x >> 6;
    const int lane = threadIdx.x & 63;
    const int rows0 = blockIdx.x * GTILE + w * 16;
    const int g  = lane >> 4;
    const int rl = lane & 15;

    f32x4 acc[8];
    #pragma unroll
    for (int c = 0; c < 8; ++c)
        acc[c] = (f32x4){0.f, 0.f, 0.f, 0.f};

    for (int t = 0; t < 4; ++t) {
        int arow = rows0 + rl;
        arow = (arow < m_rows) ? arow : (m_rows - 1);
        const short8 a = *(const short8*)(A + (size_t)arow * DH + t * 32 + g * 8);
        #pragma unroll
        for (int c = 0; c < 8; ++c) {
            const int fidx = ((t * 8 + c) * 64 + lane) * 8;
            const short8 bh = *(const short8*)(Wh + fidx);
            acc[c] = __builtin_amdgcn_mfma_f32_16x16x32_bf16(a, bh, acc[c], 0, 0, 0);
        }
    }

    float bb[8], gg[8], bt8[8];
    #pragma unroll
    for (int c = 0; c < 8; ++c) {
        const int col = c * 16 + rl;
        bb[c] = bias[col];  gg[c] = gam[col];  bt8[c] = bet[col];
    }
    #pragma unroll
    for (int q = 0; q < 4; ++q) {
        float v[8];
        float s = 0.f, sq = 0.f;
        #pragma unroll
        for (int c = 0; c < 8; ++c) {
            v[c] = acc[c][q] + bb[c];
            s  += v[c];
            sq  = fmaf(v[c], v[c], sq);
        }
        #pragma unroll
        for (int off = 1; off < 16; off <<= 1) {
            s  += __shfl_xor(s,  off);
            sq += __shfl_xor(sq, off);
        }
        const float mu   = s * (1.f / 128.f);
        const float var  = sq * (1.f / 128.f) - mu * mu;
        const float rstd = rsqrtf(var + LN_EPS);
        const int row = rows0 + g * 4 + q;
        if (row < m_rows) {
            #pragma unroll
            for (int c = 0; c < 8; ++c)
                out[(size_t)row * DH + c * 16 + rl] =
                    (v[c] - mu) * rstd * gg[c] + bt8[c];
        }
    }
}

// ====== fused per-node GAT: 16 lanes/edge, quarter-distributed GELU epilogue ======
__global__ __launch_bounds__(256) void gat_node_kernel(
    const int* __restrict__ rowptr, const int* __restrict__ deg,
    const unsigned short* __restrict__ csr_src,
    const unsigned short* __restrict__ xlb, const unsigned short* __restrict__ xrb,
    const float* __restrict__ att, const float* __restrict__ bias,
    const float* __restrict__ gam, const float* __restrict__ bet,
    unsigned short* __restrict__ out)
{
    const int n    = blockIdx.x * 4 + (threadIdx.x >> 6);
    const int lane = threadIdx.x & 63;
    if (n >= N_NODES) return;
    const int q  = lane >> 4;       // edge slot 0..3
    const int r  = lane & 15;       // channel group
    const int c0 = r * 8;

    const ushort8v ur = *(const ushort8v*)(xrb + ((size_t)n << 7) + c0);
    float xrv[8];
    #pragma unroll
    for (int j = 0; j < 8; ++j) xrv[j] = bf2f(ur[j]);

    float a6[8], a4[8];
    #pragma unroll
    for (int j = 0; j < 8; ++j) {
        const float a = att[c0 + j];
        a6[j] = a * (0.6f * LOG2E);
        a4[j] = a * (0.4f * LOG2E);
    }

    float dsum = 0.f;
    float p[8];
    #pragma unroll
    for (int j = 0; j < 8; ++j) p[j] = 0.f;

    const int beg = rowptr[n];
    const int end = beg + deg[n];

    int e = beg;
    bool vcur = (e + q) < end;
    int s = vcur ? (int)csr_src[e + q] : 0;
    ushort8v u = *(const ushort8v*)(xlb + ((size_t)s << 7) + c0);

    while (e < end) {
        const int en = e + 4;
        ushort8v unext = u;
        bool vnext = false;
        if (en < end) {   // wave-uniform
            vnext = (en + q) < end;
            const int sn = vnext ? (int)csr_src[en + q] : 0;
            unext = *(const ushort8v*)(xlb + ((size_t)sn << 7) + c0);
        }
        float x[8];
        #pragma unroll
        for (int j = 0; j < 8; ++j) x[j] = bf2f(u[j]);
        float l = 0.f;
        #pragma unroll
        for (int j = 0; j < 8; ++j) {
            const float t = x[j] + xrv[j];
            l = fmaf(a6[j], t, fmaf(a4[j], fabsf(t), l));
        }
        l += __shfl_xor(l, 1);
        l += __shfl_xor(l, 2);
        l = vcur ? l : -INFINITY;
        const float w = exp2f(l);
        dsum += w;
        #pragma unroll
        for (int j = 0; j < 8; ++j) p[j] = fmaf(x[j], w, p[j]);

        u = unext; vcur = vnext; e = en;
    }

    dsum += __shfl_xor(dsum, 16);
    dsum += __shfl_xor(dsum, 32);
    #pragma unroll
    for (int j = 0; j < 8; ++j) {
        p[j] += __shfl_xor(p[j], 16);
        p[j] += __shfl_xor(p[j], 32);
    }

    const float inv = 1.f / dsum;
    float v[8];
    float s2 = 0.f, sq = 0.f;
    #pragma unroll
    for (int j = 0; j < 8; ++j) {
        v[j] = p[j] * inv + bias[c0 + j];
        s2 += v[j];
        sq  = fmaf(v[j], v[j], sq);
    }
    #pragma unroll
    for (int off = 1; off < 16; off <<= 1) {
        s2 += __shfl_xor(s2, off);
        sq += __shfl_xor(sq, off);
    }
    const float mu   = s2 * (1.f / 128.f);
    const float var  = sq * (1.f / 128.f) - mu * mu;
    const float rstd = rsqrtf(var + LN_EPS);

    const int j0 = q * 2;
    const float ya = gelu_exact((v[j0]     - mu) * rstd * gam[c0 + j0]     + bet[c0 + j0]);
    const float yb = gelu_exact((v[j0 + 1] - mu) * rstd * gam[c0 + j0 + 1] + bet[c0 + j0 + 1]);
    ((unsigned*)out)[(size_t)n * 64 + r * 4 + q] = pk_bf16(ya, yb);
}

extern "C" void kernel_launch(void* const* d_in, const int* in_sizes, int n_in,
                              void* d_out, int out_size, void* d_ws, size_t ws_size,
                              hipStream_t stream)
{
    const float* x    = (const float*)d_in[0];
    const int*   eidx = (const int*)  d_in[1];

    const float* Wl[2]   = { (const float*)d_in[2],  (const float*)d_in[10] };
    const float* bl[2]   = { (const float*)d_in[3],  (const float*)d_in[11] };
    const float* Wr[2]   = { (const float*)d_in[4],  (const float*)d_in[12] };
    const float* br[2]   = { (const float*)d_in[5],  (const float*)d_in[13] };
    const float* att[2]  = { (const float*)d_in[6],  (const float*)d_in[14] };
    const float* bias[2] = { (const float*)d_in[7],  (const float*)d_in[15] };
    const float* gam[2]  = { (const float*)d_in[8],  (const float*)d_in[16] };
    const float* bet[2]  = { (const float*)d_in[9],  (const float*)d_in[17] };
    const float* Wout    = (const float*)d_in[18];
    const float* bout    = (const float*)d_in[19];
    const float* gout    = (const float*)d_in[20];
    const float* boutln  = (const float*)d_in[21];

    float* out = (float*)d_out;

    const size_t NF = (size_t)N_NODES * DH;
    unsigned short* xb  = (unsigned short*)d_ws;       // NF bf16 (x converted)
    unsigned short* xlb = xb + NF;                     // NF bf16 (gather operand)
    unsigned short* xrb = xlb + NF;                    // NF bf16
    unsigned short* hb  = xrb + NF;                    // NF bf16 (hidden act)
    unsigned short* csr_src = hb + NF;                 // ETOT u16
    unsigned short* rank16  = csr_src + ETOT + 16;     // ETOT u16
    int*   deg     = (int*)(rank16 + ETOT + 16);
    int*   rowptr  = deg + N_NODES;
    short* whi     = (short*)(rowptr + N_NODES);   // 5 * 16384 shorts (bf16 only)

    const int nodeBlocks = N_NODES / 4;
    const int gemmBlocks = (N_NODES + GTILE - 1) / GTILE; // 782
    const int pdBlocks   = 2 * DRBLK + (PPARTS - DRBLK);  // 6766
    const int scgeBlocks = SCBLK + 2 * gemmBlocks;        // 416 + 1564

    #define WPH(i) (whi + (i) * 16384)

    // ---- fused prep + degree/rank (interleaved blocks; deg zeroed first) ----
    hipMemsetAsync(deg, 0, N_NODES * sizeof(int), stream);
    prep_degree_kernel<<<pdBlocks, 256, 0, stream>>>(
        Wl[0], Wr[0], Wl[1], Wr[1], Wout, whi, x, xb, eidx, deg, rank16);

    // ---- CSR prefix (single kernel) ----
    rowptr_kernel<<<NBLK, 256, 0, stream>>>(deg, rowptr);

    // ---- fused: scatter + layer-0 dual GEMM ----
    scatter_gemm2_kernel<<<scgeBlocks, 256, 0, stream>>>(
        eidx, rowptr, rank16, csr_src,
        xb, N_NODES, WPH(0), bl[0], xlb, WPH(1), br[0], xrb);

    // ---- layer 0 GAT ----
    gat_node_kernel<<<nodeBlocks, 256, 0, stream>>>(rowptr, deg, csr_src, xlb, xrb,
                                                    att[0], bias[0], gam[0], bet[0], hb);
    // ---- layer 1 ----
    gemm2_kernel<<<dim3(gemmBlocks, 2), 256, 0, stream>>>(
        hb, N_NODES, WPH(2), bl[1], xlb, WPH(3), br[1], xrb);
    gat_node_kernel<<<nodeBlocks, 256, 0, stream>>>(rowptr, deg, csr_src, xlb, xrb,
                                                    att[1], bias[1], gam[1], bet[1], hb);

    // ---- output projection + fused final LayerNorm ----
    gemm1_ln_kernel<<<gemmBlocks, 256, 0, stream>>>(
        hb, N_NODES, WPH(4), bout, gout, boutln, out);
}

// Round 24
// 200.587 us; speedup vs baseline: 1.1144x; 1.1144x over previous
//
#include <hip/hip_runtime.h>
#include <math.h>

#define N_NODES 50000
#define N_EDGES 800000
#define ETOT    (N_EDGES + N_NODES)
#define DH      128
#define NH      4
#define LN_EPS  1e-5f
#define NBLK    ((N_NODES + 255) / 256)   // 196 scan blocks
#define LOG2E   1.4426950408889634f

typedef __attribute__((ext_vector_type(8))) short short8;
typedef __attribute__((ext_vector_type(8))) unsigned short ushort8v;
typedef __attribute__((ext_vector_type(4))) float f32x4;
typedef __attribute__((ext_vector_type(4))) unsigned uint4v;

// ---------- fp32 -> bf16 (RNE) helpers ----------
__device__ __forceinline__ unsigned short f2bf(float f) {
    unsigned u = __float_as_uint(f);
    u += 0x7FFFu + ((u >> 16) & 1u);
    return (unsigned short)(u >> 16);
}
__device__ __forceinline__ float bf2f(unsigned short h) {
    return __uint_as_float(((unsigned)h) << 16);
}
__device__ __forceinline__ unsigned pk_bf16(float a, float b) {
    unsigned h;
    asm("v_cvt_pk_bf16_f32 %0, %1, %2" : "=v"(h) : "v"(a), "v"(b));
    return h;
}

// ---------- fast exact-GELU (A&S 7.1.26 erf, max err ~1.5e-7) ----------
__device__ __forceinline__ float gelu_exact(float x) {
    const float z  = x * 0.70710678118654752f;
    const float az = fabsf(z);
    const float tt = __builtin_amdgcn_rcpf(fmaf(0.3275911f, az, 1.f));
    float p = fmaf(1.061405429f, tt, -1.453152027f);
    p = fmaf(p, tt, 1.421413741f);
    p = fmaf(p, tt, -0.284496736f);
    p = fmaf(p, tt, 0.254829592f);
    p = p * tt;
    const float ez = exp2f(-(z * z) * LOG2E);
    float er = fmaf(-p, ez, 1.f);
    er = copysignf(er, z);
    return x * fmaf(0.5f, er, 0.5f);
}

// ===== fused prep+degree, INTERLEAVED block ranges =====
// drBlocks = 3321 (1 edge/thread), prepParts = 3445 (320 W-pack + 3125 x-convert)
// block ids [0, 6642): odd -> degree chunk (b>>1), even -> prep part (b>>1)
// block ids [6642, 6766): prep parts 3321..3445
#define DRBLK  ((ETOT + 255) / 256)        // 3321
#define PPARTS (320 + 3125)                // 3445
__global__ __launch_bounds__(256) void prep_degree_kernel(
    const float* __restrict__ W0, const float* __restrict__ W1,
    const float* __restrict__ W2, const float* __restrict__ W3,
    const float* __restrict__ W4,
    short* __restrict__ hi,
    const float* __restrict__ X, unsigned short* __restrict__ Xb,
    const int* __restrict__ eidx, int* __restrict__ deg,
    unsigned short* __restrict__ rank16)
{
    const int b = blockIdx.x;
    int pp = -1;
    if (b < 2 * DRBLK) {
        if (b & 1) {
            // degree/rank chunk
            const int i = (b >> 1) * 256 + threadIdx.x;
            if (i < ETOT) {
                const int d = (i < N_EDGES) ? eidx[N_EDGES + i] : (i - N_EDGES);
                rank16[i] = (unsigned short)atomicAdd(&deg[d], 1);
            }
            return;
        }
        pp = b >> 1;
    } else {
        pp = b - DRBLK;   // 3321..3444
    }
    if (pp < 320) {
        const int idx = pp * 256 + threadIdx.x;   // 0..81919
        const int mat = idx >> 14;
        const int rem = idx & 16383;
        const int t = rem >> 12, c = (rem >> 9) & 7, l = (rem >> 3) & 63, j = rem & 7;
        const int k = t * 32 + (l >> 4) * 8 + j;
        const int n = c * 16 + (l & 15);
        const float* W = (mat == 0) ? W0 : (mat == 1) ? W1 : (mat == 2) ? W2
                       : (mat == 3) ? W3 : W4;
        hi[idx] = (short)f2bf(W[k * DH + n]);
    } else {
        const size_t i = ((size_t)(pp - 320) * 256 + threadIdx.x) * 8;   // NF = 3125*2048
        const float4 f0 = *(const float4*)(X + i);
        const float4 f1 = *(const float4*)(X + i + 4);
        uint4v o;
        o[0] = pk_bf16(f0.x, f0.y);
        o[1] = pk_bf16(f0.z, f0.w);
        o[2] = pk_bf16(f1.x, f1.y);
        o[3] = pk_bf16(f1.z, f1.w);
        *(uint4v*)(Xb + i) = o;
    }
}

// ========== CSR: block sums of deg ==========
__global__ __launch_bounds__(256) void block_sum_kernel(
    const int* __restrict__ deg, int* __restrict__ bsum)
{
    const int i    = blockIdx.x * 256 + threadIdx.x;
    const int lane = threadIdx.x & 63;
    const int wid  = threadIdx.x >> 6;
    int v = (i < N_NODES) ? deg[i] : 0;
    #pragma unroll
    for (int off = 32; off; off >>= 1) v += __shfl_xor(v, off);
    __shared__ int ws[4];
    if (lane == 0) ws[wid] = v;
    __syncthreads();
    if (threadIdx.x == 0) bsum[blockIdx.x] = ws[0] + ws[1] + ws[2] + ws[3];
}

// ===== rowptr with inline scan of block sums =====
__global__ __launch_bounds__(256) void rowptr_kernel(
    const int* __restrict__ deg, const int* __restrict__ bsum,
    int* __restrict__ rowptr)
{
    const int b    = blockIdx.x;
    const int tid  = threadIdx.x;
    const int lane = tid & 63;
    const int wid  = tid >> 6;

    int bv = (tid < b) ? bsum[tid] : 0;   // NBLK=196 < 256
    #pragma unroll
    for (int off = 32; off; off >>= 1) bv += __shfl_xor(bv, off);
    __shared__ int ws2[4];
    __shared__ int boffs;
    if (lane == 0) ws2[wid] = bv;
    __syncthreads();
    if (tid == 0) boffs = ws2[0] + ws2[1] + ws2[2] + ws2[3];
    __syncthreads();
    const int boff = boffs;

    const int i = b * 256 + tid;
    int v = (i < N_NODES) ? deg[i] : 0;
    int inc = v;
    #pragma unroll
    for (int off = 1; off < 64; off <<= 1) {
        int u = __shfl_up(inc, off);
        if (lane >= off) inc += u;
    }
    __shared__ int ws[4];
    if (lane == 63) ws[wid] = inc;
    __syncthreads();
    int add = boff;
    for (int w = 0; w < wid; ++w) add += ws[w];
    if (i < N_NODES) rowptr[i] = add + inc - v;
}

// ========== fused: atomic-free scatter + layer-0 dual GEMM (bf16 W) ==========
#define GTILE 64
#define SCBLK ((ETOT / 8 + 255) / 256)   // 416
__global__ __launch_bounds__(256) void scatter_gemm2_kernel(
    const int* __restrict__ eidx, const int* __restrict__ rowptr,
    const unsigned short* __restrict__ rank16, unsigned short* __restrict__ csr_src,
    const unsigned short* __restrict__ A, int m_rows,
    const short* __restrict__ WhL, const float* __restrict__ biasL,
    unsigned short* __restrict__ YL,
    const short* __restrict__ WhR, const float* __restrict__ biasR,
    unsigned short* __restrict__ YR)
{
    if (blockIdx.x < SCBLK) {
        const int base = (blockIdx.x * 256 + threadIdx.x) * 8;
        if (base < N_EDGES) {
            const int4 s0 = *(const int4*)(eidx + base);
            const int4 s1 = *(const int4*)(eidx + base + 4);
            const int4 d0 = *(const int4*)(eidx + N_EDGES + base);
            const int4 d1 = *(const int4*)(eidx + N_EDGES + base + 4);
            const ushort8v rk = *(const ushort8v*)(rank16 + base);
            csr_src[rowptr[d0.x] + rk[0]] = (unsigned short)s0.x;
            csr_src[rowptr[d0.y] + rk[1]] = (unsigned short)s0.y;
            csr_src[rowptr[d0.z] + rk[2]] = (unsigned short)s0.z;
            csr_src[rowptr[d0.w] + rk[3]] = (unsigned short)s0.w;
            csr_src[rowptr[d1.x] + rk[4]] = (unsigned short)s1.x;
            csr_src[rowptr[d1.y] + rk[5]] = (unsigned short)s1.y;
            csr_src[rowptr[d1.z] + rk[6]] = (unsigned short)s1.z;
            csr_src[rowptr[d1.w] + rk[7]] = (unsigned short)s1.w;
        } else if (base < ETOT) {
            const int d0 = base - N_EDGES;
            const ushort8v rk = *(const ushort8v*)(rank16 + base);
            #pragma unroll
            for (int k = 0; k < 8; ++k)
                csr_src[rowptr[d0 + k] + rk[k]] = (unsigned short)(d0 + k);
        }
        return;
    }

    const int gb   = blockIdx.x - SCBLK;
    const int w    = threadIdx.x >> 6;
    const int lane = threadIdx.x & 63;
    const int rows0 = (gb >> 1) * GTILE + w * 16;
    const int ch   = gb & 1;
    const int g  = lane >> 4;
    const int rl = lane & 15;

    f32x4 accL[4], accR[4];
    #pragma unroll
    for (int c = 0; c < 4; ++c) {
        accL[c] = (f32x4){0.f, 0.f, 0.f, 0.f};
        accR[c] = (f32x4){0.f, 0.f, 0.f, 0.f};
    }

    for (int t = 0; t < 4; ++t) {
        int arow = rows0 + rl;
        arow = (arow < m_rows) ? arow : (m_rows - 1);
        const short8 a = *(const short8*)(A + (size_t)arow * DH + t * 32 + g * 8);
        #pragma unroll
        for (int c = 0; c < 4; ++c) {
            const int cc = ch * 4 + c;
            const int fidx = ((t * 8 + cc) * 64 + lane) * 8;
            const short8 bL = *(const short8*)(WhL + fidx);
            const short8 bR = *(const short8*)(WhR + fidx);
            accL[c] = __builtin_amdgcn_mfma_f32_16x16x32_bf16(a, bL, accL[c], 0, 0, 0);
            accR[c] = __builtin_amdgcn_mfma_f32_16x16x32_bf16(a, bR, accR[c], 0, 0, 0);
        }
    }
    #pragma unroll
    for (int c = 0; c < 4; ++c) {
        const int col = (ch * 4 + c) * 16 + rl;
        const float bL = biasL[col];
        const float bR = biasR[col];
        #pragma unroll
        for (int q = 0; q < 4; ++q) {
            const int row = rows0 + g * 4 + q;
            if (row < m_rows) {
                YL[(size_t)row * DH + col] = f2bf(accL[c][q] + bL);
                YR[(size_t)row * DH + col] = f2bf(accR[c][q] + bR);
            }
        }
    }
}

// ========== standalone dual GEMM (layer 1, bf16 W) ==========
__global__ __launch_bounds__(256) void gemm2_kernel(
    const unsigned short* __restrict__ A, int m_rows,
    const short* __restrict__ WhL, const float* __restrict__ biasL,
    unsigned short* __restrict__ YL,
    const short* __restrict__ WhR, const float* __restrict__ biasR,
    unsigned short* __restrict__ YR)
{
    const int w    = threadIdx.x >> 6;
    const int lane = threadIdx.x & 63;
    const int rows0 = blockIdx.x * GTILE + w * 16;
    const int ch   = blockIdx.y;
    const int g  = lane >> 4;
    const int rl = lane & 15;

    f32x4 accL[4], accR[4];
    #pragma unroll
    for (int c = 0; c < 4; ++c) {
        accL[c] = (f32x4){0.f, 0.f, 0.f, 0.f};
        accR[c] = (f32x4){0.f, 0.f, 0.f, 0.f};
    }

    for (int t = 0; t < 4; ++t) {
        int arow = rows0 + rl;
        arow = (arow < m_rows) ? arow : (m_rows - 1);
        const short8 a = *(const short8*)(A + (size_t)arow * DH + t * 32 + g * 8);
        #pragma unroll
        for (int c = 0; c < 4; ++c) {
            const int cc = ch * 4 + c;
            const int fidx = ((t * 8 + cc) * 64 + lane) * 8;
            const short8 bL = *(const short8*)(WhL + fidx);
            const short8 bR = *(const short8*)(WhR + fidx);
            accL[c] = __builtin_amdgcn_mfma_f32_16x16x32_bf16(a, bL, accL[c], 0, 0, 0);
            accR[c] = __builtin_amdgcn_mfma_f32_16x16x32_bf16(a, bR, accR[c], 0, 0, 0);
        }
    }
    #pragma unroll
    for (int c = 0; c < 4; ++c) {
        const int col = (ch * 4 + c) * 16 + rl;
        const float bL = biasL[col];
        const float bR = biasR[col];
        #pragma unroll
        for (int q = 0; q < 4; ++q) {
            const int row = rows0 + g * 4 + q;
            if (row < m_rows) {
                YL[(size_t)row * DH + col] = f2bf(accL[c][q] + bL);
                YR[(size_t)row * DH + col] = f2bf(accR[c][q] + bR);
            }
        }
    }
}

// ========== gemm1 + fused final LayerNorm: 16 rows/wave (bf16 W) ==========
__global__ __launch_bounds__(256) void gemm1_ln_kernel(
    const unsigned short* __restrict__ A, int m_rows,
    const short* __restrict__ Wh, const float* __restrict__ bias,
    const float* __restrict__ gam, const float* __restrict__ bet,
    float* __restrict__ out)
{
    const int w    = threadIdx.x >> 6;
    const int lane = threadIdx.x & 63;
    const int rows0 = blockIdx.x * GTILE + w * 16;
    const int g  = lane >> 4;
    const int rl = lane & 15;

    f32x4 acc[8];
    #pragma unroll
    for (int c = 0; c < 8; ++c)
        acc[c] = (f32x4){0.f, 0.f, 0.f, 0.f};

    for (int t = 0; t < 4; ++t) {
        int arow = rows0 + rl;
        arow = (arow < m_rows) ? arow : (m_rows - 1);
        const short8 a = *(const short8*)(A + (size_t)arow * DH + t * 32 + g * 8);
        #pragma unroll
        for (int c = 0; c < 8; ++c) {
            const int fidx = ((t * 8 + c) * 64 + lane) * 8;
            const short8 bh = *(const short8*)(Wh + fidx);
            acc[c] = __builtin_amdgcn_mfma_f32_16x16x32_bf16(a, bh, acc[c], 0, 0, 0);
        }
    }

    float bb[8], gg[8], bt8[8];
    #pragma unroll
    for (int c = 0; c < 8; ++c) {
        const int col = c * 16 + rl;
        bb[c] = bias[col];  gg[c] = gam[col];  bt8[c] = bet[col];
    }
    #pragma unroll
    for (int q = 0; q < 4; ++q) {
        float v[8];
        float s = 0.f, sq = 0.f;
        #pragma unroll
        for (int c = 0; c < 8; ++c) {
            v[c] = acc[c][q] + bb[c];
            s  += v[c];
            sq  = fmaf(v[c], v[c], sq);
        }
        #pragma unroll
        for (int off = 1; off < 16; off <<= 1) {
            s  += __shfl_xor(s,  off);
            sq += __shfl_xor(sq, off);
        }
        const float mu   = s * (1.f / 128.f);
        const float var  = sq * (1.f / 128.f) - mu * mu;
        const float rstd = rsqrtf(var + LN_EPS);
        const int row = rows0 + g * 4 + q;
        if (row < m_rows) {
            #pragma unroll
            for (int c = 0; c < 8; ++c)
                out[(size_t)row * DH + c * 16 + rl] =
                    (v[c] - mu) * rstd * gg[c] + bt8[c];
        }
    }
}

// ====== fused per-node GAT: 16 lanes/edge, quarter-distributed GELU epilogue ======
__global__ __launch_bounds__(256) void gat_node_kernel(
    const int* __restrict__ rowptr, const int* __restrict__ deg,
    const unsigned short* __restrict__ csr_src,
    const unsigned short* __restrict__ xlb, const unsigned short* __restrict__ xrb,
    const float* __restrict__ att, const float* __restrict__ bias,
    const float* __restrict__ gam, const float* __restrict__ bet,
    unsigned short* __restrict__ out)
{
    const int n    = blockIdx.x * 4 + (threadIdx.x >> 6);
    const int lane = threadIdx.x & 63;
    if (n >= N_NODES) return;
    const int q  = lane >> 4;       // edge slot 0..3
    const int r  = lane & 15;       // channel group
    const int c0 = r * 8;

    const ushort8v ur = *(const ushort8v*)(xrb + ((size_t)n << 7) + c0);
    float xrv[8];
    #pragma unroll
    for (int j = 0; j < 8; ++j) xrv[j] = bf2f(ur[j]);

    float a6[8], a4[8];
    #pragma unroll
    for (int j = 0; j < 8; ++j) {
        const float a = att[c0 + j];
        a6[j] = a * (0.6f * LOG2E);
        a4[j] = a * (0.4f * LOG2E);
    }

    float dsum = 0.f;
    float p[8];
    #pragma unroll
    for (int j = 0; j < 8; ++j) p[j] = 0.f;

    const int beg = rowptr[n];
    const int end = beg + deg[n];

    int e = beg;
    bool vcur = (e + q) < end;
    int s = vcur ? (int)csr_src[e + q] : 0;
    ushort8v u = *(const ushort8v*)(xlb + ((size_t)s << 7) + c0);

    while (e < end) {
        const int en = e + 4;
        ushort8v unext = u;
        bool vnext = false;
        if (en < end) {   // wave-uniform
            vnext = (en + q) < end;
            const int sn = vnext ? (int)csr_src[en + q] : 0;
            unext = *(const ushort8v*)(xlb + ((size_t)sn << 7) + c0);
        }
        float x[8];
        #pragma unroll
        for (int j = 0; j < 8; ++j) x[j] = bf2f(u[j]);
        float l = 0.f;
        #pragma unroll
        for (int j = 0; j < 8; ++j) {
            const float t = x[j] + xrv[j];
            l = fmaf(a6[j], t, fmaf(a4[j], fabsf(t), l));
        }
        l += __shfl_xor(l, 1);
        l += __shfl_xor(l, 2);
        l = vcur ? l : -INFINITY;
        const float w = exp2f(l);
        dsum += w;
        #pragma unroll
        for (int j = 0; j < 8; ++j) p[j] = fmaf(x[j], w, p[j]);

        u = unext; vcur = vnext; e = en;
    }

    dsum += __shfl_xor(dsum, 16);
    dsum += __shfl_xor(dsum, 32);
    #pragma unroll
    for (int j = 0; j < 8; ++j) {
        p[j] += __shfl_xor(p[j], 16);
        p[j] += __shfl_xor(p[j], 32);
    }

    const float inv = 1.f / dsum;
    float v[8];
    float s2 = 0.f, sq = 0.f;
    #pragma unroll
    for (int j = 0; j < 8; ++j) {
        v[j] = p[j] * inv + bias[c0 + j];
        s2 += v[j];
        sq  = fmaf(v[j], v[j], sq);
    }
    #pragma unroll
    for (int off = 1; off < 16; off <<= 1) {
        s2 += __shfl_xor(s2, off);
        sq += __shfl_xor(sq, off);
    }
    const float mu   = s2 * (1.f / 128.f);
    const float var  = sq * (1.f / 128.f) - mu * mu;
    const float rstd = rsqrtf(var + LN_EPS);

    const int j0 = q * 2;
    const float ya = gelu_exact((v[j0]     - mu) * rstd * gam[c0 + j0]     + bet[c0 + j0]);
    const float yb = gelu_exact((v[j0 + 1] - mu) * rstd * gam[c0 + j0 + 1] + bet[c0 + j0 + 1]);
    ((unsigned*)out)[(size_t)n * 64 + r * 4 + q] = pk_bf16(ya, yb);
}

extern "C" void kernel_launch(void* const* d_in, const int* in_sizes, int n_in,
                              void* d_out, int out_size, void* d_ws, size_t ws_size,
                              hipStream_t stream)
{
    const float* x    = (const float*)d_in[0];
    const int*   eidx = (const int*)  d_in[1];

    const float* Wl[2]   = { (const float*)d_in[2],  (const float*)d_in[10] };
    const float* bl[2]   = { (const float*)d_in[3],  (const float*)d_in[11] };
    const float* Wr[2]   = { (const float*)d_in[4],  (const float*)d_in[12] };
    const float* br[2]   = { (const float*)d_in[5],  (const float*)d_in[13] };
    const float* att[2]  = { (const float*)d_in[6],  (const float*)d_in[14] };
    const float* bias[2] = { (const float*)d_in[7],  (const float*)d_in[15] };
    const float* gam[2]  = { (const float*)d_in[8],  (const float*)d_in[16] };
    const float* bet[2]  = { (const float*)d_in[9],  (const float*)d_in[17] };
    const float* Wout    = (const float*)d_in[18];
    const float* bout    = (const float*)d_in[19];
    const float* gout    = (const float*)d_in[20];
    const float* boutln  = (const float*)d_in[21];

    float* out = (float*)d_out;

    const size_t NF = (size_t)N_NODES * DH;
    unsigned short* xb  = (unsigned short*)d_ws;       // NF bf16 (x converted)
    unsigned short* xlb = xb + NF;                     // NF bf16 (gather operand)
    unsigned short* xrb = xlb + NF;                    // NF bf16
    unsigned short* hb  = xrb + NF;                    // NF bf16 (hidden act)
    unsigned short* csr_src = hb + NF;                 // ETOT u16
    unsigned short* rank16  = csr_src + ETOT + 16;     // ETOT u16
    int*   deg     = (int*)(rank16 + ETOT + 16);
    int*   rowptr  = deg + N_NODES;
    int*   bsum    = rowptr + N_NODES;
    short* whi     = (short*)(bsum + NBLK);   // 5 * 16384 shorts (bf16 only)

    const int nodeBlocks = N_NODES / 4;
    const int gemmBlocks = (N_NODES + GTILE - 1) / GTILE; // 782
    const int pdBlocks   = 2 * DRBLK + (PPARTS - DRBLK);  // 6642 + 124 = 6766
    const int scgeBlocks = SCBLK + 2 * gemmBlocks;        // 416 + 1564

    #define WPH(i) (whi + (i) * 16384)

    // ---- fused prep + degree/rank (interleaved blocks; deg zeroed first) ----
    hipMemsetAsync(deg, 0, N_NODES * sizeof(int), stream);
    prep_degree_kernel<<<pdBlocks, 256, 0, stream>>>(
        Wl[0], Wr[0], Wl[1], Wr[1], Wout, whi, x, xb, eidx, deg, rank16);

    // ---- CSR prefix ----
    block_sum_kernel<<<NBLK, 256, 0, stream>>>(deg, bsum);
    rowptr_kernel   <<<NBLK, 256, 0, stream>>>(deg, bsum, rowptr);

    // ---- fused: scatter + layer-0 dual GEMM ----
    scatter_gemm2_kernel<<<scgeBlocks, 256, 0, stream>>>(
        eidx, rowptr, rank16, csr_src,
        xb, N_NODES, WPH(0), bl[0], xlb, WPH(1), br[0], xrb);

    // ---- layer 0 GAT ----
    gat_node_kernel<<<nodeBlocks, 256, 0, stream>>>(rowptr, deg, csr_src, xlb, xrb,
                                                    att[0], bias[0], gam[0], bet[0], hb);
    // ---- layer 1 ----
    gemm2_kernel<<<dim3(gemmBlocks, 2), 256, 0, stream>>>(
        hb, N_NODES, WPH(2), bl[1], xlb, WPH(3), br[1], xrb);
    gat_node_kernel<<<nodeBlocks, 256, 0, stream>>>(rowptr, deg, csr_src, xlb, xrb,
                                                    att[1], bias[1], gam[1], bet[1], hb);

    // ---- output projection + fused final LayerNorm ----
    gemm1_ln_kernel<<<gemmBlocks, 256, 0, stream>>>(
        hb, N_NODES, WPH(4), bout, gout, boutln, out);
}